// Round 17
// baseline (90.823 us; speedup 1.0000x reference)
//
#include <hip/hip_runtime.h>
#include <hip/hip_bf16.h>

#define V 17
#define C_DIM 256
#define TV 1088        // T*V
#define CTV 278528     // C*T*V
#define N_TILES 1024
#define XG_OFF 1048576u            // Xg at ws+1MB
#define XG_HPT 20480               // halves per tile = 80*256
#define WS_NEEDED (XG_OFF + (size_t)N_TILES * XG_HPT * 2)

typedef __attribute__((ext_vector_type(8))) short short8;
typedef __attribute__((ext_vector_type(4))) short svec4;
typedef __attribute__((ext_vector_type(4))) float f32x4;

static __device__ inline short f2bfs(float f) {
    union { __hip_bfloat16 b; short s; } u;
    u.b = __float2bfloat16(f);
    return u.s;
}
static __device__ inline float bfs2f(short s) {
    union { float f; unsigned u; } q;
    q.u = ((unsigned)(unsigned short)s) << 16;
    return q.f;
}

// ws layout (bytes):
//   0      : wtb (65536 bf16)  blocked W^T: wtb[(kc*256+d)*32+kk] = W[kc*32+kk][d]
//   131072 : g   (4352 f32)    tanh(fm)+1
//   148480 : scl (4352 f32)    [u][d] = gamma[v,d]/sqrt(var[v,d]+eps),  v=(u+d)%17
//   165888 : ofs (4352 f32)    [u][d] = (lin_b[d]-mean[v,d])*scl+beta[v,d]
//   183296 : gnv (4352 f32)    [u][d] = 1/g[u][d]
//   1 MB   : Xg  (41.9 MB bf16) gated+shifted A, GEMM-fragment layout
__global__ __launch_bounds__(256) void prep_kernel(
    const float* __restrict__ fm, const float* __restrict__ W,
    const float* __restrict__ lb, const float* __restrict__ gamma,
    const float* __restrict__ beta, const float* __restrict__ mean,
    const float* __restrict__ var,
    __hip_bfloat16* __restrict__ wtb, float* __restrict__ g,
    float* __restrict__ scl, float* __restrict__ ofs, float* __restrict__ gnv)
{
    int i = blockIdx.x * 256 + threadIdx.x;   // 65536 threads
    int c = i >> 8, d = i & 255;
    float w = W[i];
    wtb[((c >> 5) * 256 + d) * 32 + (c & 31)] = __float2bfloat16(w);
    if (i < V * C_DIM) {
        float gv = tanhf(fm[i]) + 1.0f;
        g[i]   = gv;
        gnv[i] = 1.0f / gv;
        int u = i >> 8;                        // GEMM-row joint
        int v = u + d; v %= V;                 // OUTPUT joint = (u+d) mod 17
        int k = v * C_DIM + d;                 // BN parameter index
        float sc = gamma[k] * rsqrtf(var[k] + 1e-5f);
        scl[i] = sc;
        ofs[i] = (lb[d] - mean[k]) * sc + beta[k];
    }
}

// K1: build Xg. task = tile*2560 + s8*80 + r; Xg[task] (short8) =
//   r<68 ? bf16( x0[n, c0+i, tb+tl, (u+c0+i)%17] * g[u][c0+i] ) : 0
// Reads coalesce (fixed s8 -> consecutive r = consecutive addrs);
// writes are contiguous 16B. No LDS, no barriers, full occupancy.
__global__ __launch_bounds__(256) void xg_kernel(
    const float* __restrict__ x0, const float* __restrict__ g,
    short* __restrict__ xg)
{
    int task = blockIdx.x * 256 + threadIdx.x;     // 2,621,440
    int tile = task / 2560;
    int rem  = task - tile * 2560;
    int s8   = rem / 80;                            // channel slot (8 ch)
    int r    = rem - s8 * 80;                       // GEMM row in tile
    short8 o = (short8)0;
    if (r < 68) {
        int n  = tile >> 4;
        int tb = (tile & 15) * 4;
        int tl = r / 17;
        int u  = r - tl * 17;
        int c0 = s8 * 8;
        const float* gp = g + u * C_DIM + c0;
        float4 g0 = *(const float4*)gp;
        float4 g1 = *(const float4*)(gp + 4);
        float gg[8] = {g0.x, g0.y, g0.z, g0.w, g1.x, g1.y, g1.z, g1.w};
        const float* xb = x0 + n * CTV + (tb + tl) * V;
        int mm = (u + c0) % V;
        float xv[8];
        #pragma unroll
        for (int i = 0; i < 8; ++i) {
            xv[i] = xb[(c0 + i) * TV + mm];
            mm = (mm == V - 1) ? 0 : mm + 1;
        }
        short av[8];
        #pragma unroll
        for (int i = 0; i < 8; ++i) av[i] = f2bfs(xv[i] * gg[i]);
        o = (short8){av[0], av[1], av[2], av[3], av[4], av[5], av[6], av[7]};
    }
    *(short8*)(xg + task * 8) = o;
}

// K2: LDS-free, barrier-free GEMM + fused epilogue.
// Block = tile (68 rows, padded 80) x 256 d; 512 thr / 8 waves; wave wv owns
// d in [wv*32,+32). A-fragments and residual read straight from Xg (L2/L3-hot).
// MFMA swapped operands (verified r10..r16): arg0=wfr (out row = d at lq*4+rg),
// arg1=a (out col = GEMM row at l15). Epilogue applies output shift
// v=(pos%17+d)%17; residual x0 = Xg*(1/g).
__global__ __launch_bounds__(512, 4) void gemm_kernel(
    const short* __restrict__ xg, const __hip_bfloat16* __restrict__ wtb,
    const float* __restrict__ scl, const float* __restrict__ ofs,
    const float* __restrict__ gnv, float* __restrict__ out)
{
    const int tid  = threadIdx.x;
    const int lane = tid & 63;
    const int wv   = tid >> 6;                // 0..7
    const int l15  = lane & 15;
    const int lq   = lane >> 4;

    // T1: 1024 wg = 8 XCD x 128 contiguous tiles (bijective)
    const int wg = (blockIdx.x & 7) * 128 + (blockIdx.x >> 3);
    const int n  = wg >> 4;
    const int tb = (wg & 15) * 4;
    const short* xt = xg + wg * XG_HPT;

    // wtb fragment base (elements): (ni,kc) -> + ni*512 + kc*8192
    const __hip_bfloat16* wbase = wtb + (((wv * 32 + l15) << 5) + lq * 8);
    short8 wc0 = *(const short8*)(wbase);
    short8 wc1 = *(const short8*)(wbase + 512);

    f32x4 acc[2][5];   // [dTile][posTile]
    #pragma unroll
    for (int ni = 0; ni < 2; ++ni)
        #pragma unroll
        for (int mi = 0; mi < 5; ++mi)
            acc[ni][mi] = (f32x4){0.f, 0.f, 0.f, 0.f};

    #pragma unroll
    for (int kc = 0; kc < 8; ++kc) {
        short8 wn0, wn1;
        if (kc < 7) {
            wn0 = *(const short8*)(wbase + (kc + 1) * 8192);
            wn1 = *(const short8*)(wbase + (kc + 1) * 8192 + 512);
        }
        short8 a[5];
        #pragma unroll
        for (int mi = 0; mi < 5; ++mi)
            a[mi] = *(const short8*)(xt +
                (((kc * 4 + lq) * 80 + mi * 16 + l15) << 3));
        #pragma unroll
        for (int mi = 0; mi < 5; ++mi) {
            acc[0][mi] = __builtin_amdgcn_mfma_f32_16x16x32_bf16(wc0, a[mi], acc[0][mi], 0, 0, 0);
            acc[1][mi] = __builtin_amdgcn_mfma_f32_16x16x32_bf16(wc1, a[mi], acc[1][mi], 0, 0, 0);
        }
        if (kc < 7) { wc0 = wn0; wc1 = wn1; }
    }

    // epilogue: pos = mi*16+l15 (joint ur = pos%17), d = wv*32+ni*16+lq*4+rg,
    // output joint vv = (ur+d)%17. Tables [ur][d] float4; residual from Xg.
    #pragma unroll
    for (int ni = 0; ni < 2; ++ni) {
        const int D0 = wv * 32 + ni * 16 + lq * 4;
        const int dm = D0 % V;
        int tl = 0, ur = l15;                 // pos = tl*17 + ur
        #pragma unroll
        for (int mi = 0; mi < 5; ++mi) {
            int pos = mi * 16 + l15;
            if (pos < 68) {
                float4 s4 = *(const float4*)(scl + ur * C_DIM + D0);
                float4 o4 = *(const float4*)(ofs + ur * C_DIM + D0);
                float4 g4 = *(const float4*)(gnv + ur * C_DIM + D0);
                float ss[4] = {s4.x, s4.y, s4.z, s4.w};
                float oo[4] = {o4.x, o4.y, o4.z, o4.w};
                float gi[4] = {g4.x, g4.y, g4.z, g4.w};
                // residual: 4 consecutive bf16 halves in Xg at (D0&7) of slot D0>>3
                svec4 a4 = *(const svec4*)(xt +
                    (((D0 >> 3) * 80 + pos) << 3) + (D0 & 7));
                int vv = ur + dm; if (vv >= V) vv -= V;
                int base2 = n * CTV + D0 * TV + (tb + tl) * V;
                #pragma unroll
                for (int rg = 0; rg < 4; ++rg) {
                    float x = bfs2f(a4[rg]) * gi[rg];
                    float val = acc[ni][mi][rg] * ss[rg] + oo[rg] + x;
                    out[base2 + rg * TV + vv] = fmaxf(val, 0.f);
                    if (++vv == V) vv = 0;
                }
            }
            if (ur == 0) ur = 16; else { ur -= 1; tl += 1; }
        }
    }
}

// ---------------- fallback (r16 fused, proven 67.5 us) ----------------
struct StageRegs { float xv[8]; float gg[8]; int waddr; };

static __device__ __forceinline__ void stage_load(
    int t, const float* __restrict__ xplane, const float* __restrict__ g,
    StageRegs& s)
{
    int kkc = t / 68;
    int r   = t - kkc * 68;
    int tl  = r / 17;
    int u   = r - tl * 17;
    int c0  = kkc * 8;
    const float* gp = g + u * C_DIM + c0;
    float4 g0 = *(const float4*)gp;
    float4 g1 = *(const float4*)(gp + 4);
    s.gg[0]=g0.x; s.gg[1]=g0.y; s.gg[2]=g0.z; s.gg[3]=g0.w;
    s.gg[4]=g1.x; s.gg[5]=g1.y; s.gg[6]=g1.z; s.gg[7]=g1.w;
    const float* xb = xplane + tl * V;
    int mm = (u + c0) % V;
    #pragma unroll
    for (int i = 0; i < 8; ++i) {
        s.xv[i] = xb[(c0 + i) * TV + mm];
        mm = (mm == V - 1) ? 0 : mm + 1;
    }
    s.waddr = r * 256 + ((kkc ^ (r & 7)) << 3);
}

static __device__ __forceinline__ void stage_write(short* As, const StageRegs& s)
{
    short av[8];
    #pragma unroll
    for (int i = 0; i < 8; ++i) av[i] = f2bfs(s.xv[i] * s.gg[i]);
    *(short8*)(As + s.waddr) =
        (short8){av[0], av[1], av[2], av[3], av[4], av[5], av[6], av[7]};
}

__global__ __launch_bounds__(512, 4) void fused_kernel(
    const float* __restrict__ x0, const __hip_bfloat16* __restrict__ wtb,
    const float* __restrict__ g, const float* __restrict__ scl,
    const float* __restrict__ ofs, const float* __restrict__ gnv,
    float* __restrict__ out)
{
    __shared__ __align__(16) short As[80 * 256];

    const int tid  = threadIdx.x;
    const int lane = tid & 63;
    const int wv   = tid >> 6;
    const int l15  = lane & 15;
    const int lq   = lane >> 4;

    const int wg  = (blockIdx.x & 7) * 128 + (blockIdx.x >> 3);
    const int nt0 = wg * 4;
    const int n   = nt0 >> 6;
    const int tb  = nt0 & 63;
    const float* xplane = x0 + n * CTV + tb * V;

    if (tid < 384) ((short8*)(As + 68 * 256))[tid] = (short8)0;

    const __hip_bfloat16* wbase = wtb + (((wv * 32 + l15) << 5) + lq * 8);
    short8 wc0 = *(const short8*)(wbase);
    short8 wc1 = *(const short8*)(wbase + 512);

    StageRegs s0, s1;
    stage_load(tid,        xplane, g, s0);
    stage_load(512  + tid, xplane, g, s1);
    stage_write(As, s0);
    stage_write(As, s1);
    stage_load(1024 + tid, xplane, g, s0);
    stage_load(1536 + tid, xplane, g, s1);
    stage_write(As, s0);
    stage_write(As, s1);
    if (tid < 128) {
        stage_load(2048 + tid, xplane, g, s0);
        stage_write(As, s0);
    }
    __syncthreads();

    f32x4 acc[2][5];
    #pragma unroll
    for (int ni = 0; ni < 2; ++ni)
        #pragma unroll
        for (int mi = 0; mi < 5; ++mi)
            acc[ni][mi] = (f32x4){0.f, 0.f, 0.f, 0.f};

    #pragma unroll
    for (int kc = 0; kc < 8; ++kc) {
        short8 wn0, wn1;
        if (kc < 7) {
            wn0 = *(const short8*)(wbase + (kc + 1) * 8192);
            wn1 = *(const short8*)(wbase + (kc + 1) * 8192 + 512);
        }
        #pragma unroll
        for (int mi = 0; mi < 5; ++mi) {
            int row = mi * 16 + l15;
            short8 a = *(const short8*)(As + row * 256 +
                ((((kc << 2) | lq) ^ (row & 7)) << 3));
            acc[0][mi] = __builtin_amdgcn_mfma_f32_16x16x32_bf16(wc0, a, acc[0][mi], 0, 0, 0);
            acc[1][mi] = __builtin_amdgcn_mfma_f32_16x16x32_bf16(wc1, a, acc[1][mi], 0, 0, 0);
        }
        if (kc < 7) { wc0 = wn0; wc1 = wn1; }
    }

    #pragma unroll
    for (int ni = 0; ni < 2; ++ni) {
        const int D0 = wv * 32 + ni * 16 + lq * 4;
        const int dm = D0 % V;
        int tl = 0, ur = l15;
        #pragma unroll
        for (int mi = 0; mi < 5; ++mi) {
            int pos = mi * 16 + l15;
            if (pos < 68) {
                float4 s4 = *(const float4*)(scl + ur * C_DIM + D0);
                float4 o4 = *(const float4*)(ofs + ur * C_DIM + D0);
                float4 g4 = *(const float4*)(gnv + ur * C_DIM + D0);
                float ss[4] = {s4.x, s4.y, s4.z, s4.w};
                float oo[4] = {o4.x, o4.y, o4.z, o4.w};
                float gi[4] = {g4.x, g4.y, g4.z, g4.w};
                int hb = pos * 256 + ((((D0 >> 3) ^ (pos & 7)) << 3) | (D0 & 7));
                svec4 a4 = *(const svec4*)(As + hb);
                int vv = ur + dm; if (vv >= V) vv -= V;
                int base2 = n * CTV + D0 * TV + (tb + tl) * V;
                #pragma unroll
                for (int rg = 0; rg < 4; ++rg) {
                    float x = bfs2f(a4[rg]) * gi[rg];
                    float val = acc[ni][mi][rg] * ss[rg] + oo[rg] + x;
                    out[base2 + rg * TV + vv] = fmaxf(val, 0.f);
                    if (++vv == V) vv = 0;
                }
            }
            if (ur == 0) ur = 16; else { ur -= 1; tl += 1; }
        }
    }
}

extern "C" void kernel_launch(void* const* d_in, const int* in_sizes, int n_in,
                              void* d_out, int out_size, void* d_ws, size_t ws_size,
                              hipStream_t stream)
{
    const float* x0    = (const float*)d_in[0];
    const float* fm    = (const float*)d_in[1];
    const float* W     = (const float*)d_in[2];
    const float* lb    = (const float*)d_in[3];
    const float* gamma = (const float*)d_in[4];
    const float* beta  = (const float*)d_in[5];
    const float* mean  = (const float*)d_in[6];
    const float* var   = (const float*)d_in[7];
    float* out = (float*)d_out;

    char* ws = (char*)d_ws;
    __hip_bfloat16* wtb = (__hip_bfloat16*)ws;
    float* g   = (float*)(ws + 131072);
    float* scl = (float*)(ws + 148480);
    float* ofs = (float*)(ws + 165888);
    float* gnv = (float*)(ws + 183296);

    prep_kernel<<<256, 256, 0, stream>>>(fm, W, lb, gamma, beta, mean, var,
                                         wtb, g, scl, ofs, gnv);
    if (ws_size >= WS_NEEDED) {
        short* xg = (short*)(ws + XG_OFF);
        xg_kernel<<<10240, 256, 0, stream>>>(x0, g, xg);
        gemm_kernel<<<1024, 512, 0, stream>>>(xg, wtb, scl, ofs, gnv, out);
    } else {
        fused_kernel<<<1024, 512, 0, stream>>>(x0, wtb, g, scl, ofs, gnv, out);
    }
}